// Round 1
// baseline (379.463 us; speedup 1.0000x reference)
//
#include <hip/hip_runtime.h>
#include <hip/hip_bf16.h>
#include <math.h>

#define LSEQ 320
#define CS 384
#define CZ 128
#define CH 16
#define NH 12
#define PQ 4
#define PV 8
#define EPSF 1e-8f

// workspace float offsets
// q:    0        (320*192)
// k:    61440
// v:    122880
// qpt:  184320   (320*48*6)
// kpt:  276480
// vpt:  368640   (320*96*6)
// att:  552960   (12*320*320)
// cc:   1781760  (320*2400)
// total 2549760 floats = 10.2 MB

// ---------------- kernel 1: projections + frame transforms ----------------
__global__ __launch_bounds__(256) void k_proj(
    const float* __restrict__ s, const float* __restrict__ rot, const float* __restrict__ trans,
    const float* __restrict__ Wq, const float* __restrict__ bq,
    const float* __restrict__ Wkv, const float* __restrict__ bkv,
    const float* __restrict__ Wqp, const float* __restrict__ bqp,
    const float* __restrict__ Wkvp, const float* __restrict__ bkvp,
    const float* __restrict__ Wg, const float* __restrict__ bg,
    float* __restrict__ qo, float* __restrict__ ko, float* __restrict__ vo,
    float* __restrict__ qpt, float* __restrict__ kpt, float* __restrict__ vpt)
{
    const int BL = 2;
    int l0 = blockIdx.x * BL;
    int tid = threadIdx.x;
    __shared__ float ssh[BL][CS];
    __shared__ float raw[BL][1200];  // [0,288) qp raw | [288,1152) kvp raw | [1152,1200) gate

    for (int i = tid; i < BL * CS; i += 256) ssh[i / CS][i % CS] = s[l0 * CS + i];
    __syncthreads();

    for (int c = tid; c < 1776; c += 256) {
        const float* W; int nc, c0;
        if (c < 192)       { W = Wq;   nc = 192; c0 = c; }
        else if (c < 576)  { W = Wkv;  nc = 384; c0 = c - 192; }
        else if (c < 864)  { W = Wqp;  nc = 288; c0 = c - 576; }
        else if (c < 1728) { W = Wkvp; nc = 864; c0 = c - 864; }
        else               { W = Wg;   nc = 48;  c0 = c - 1728; }
        float a0 = 0.f, a1 = 0.f;
        for (int i = 0; i < CS; i++) {
            float w = W[i * nc + c0];
            a0 += ssh[0][i] * w;
            a1 += ssh[1][i] * w;
        }
        if (c < 192) {
            float b = bq[c0];
            qo[l0 * 192 + c0] = a0 + b; qo[(l0 + 1) * 192 + c0] = a1 + b;
        } else if (c < 576) {
            float b = bkv[c0]; a0 += b; a1 += b;
            if (c0 < 192) { ko[l0 * 192 + c0] = a0; ko[(l0 + 1) * 192 + c0] = a1; }
            else { vo[l0 * 192 + c0 - 192] = a0; vo[(l0 + 1) * 192 + c0 - 192] = a1; }
        } else if (c < 864) {
            float b = bqp[c0];
            raw[0][c0] = a0 + b; raw[1][c0] = a1 + b;
        } else if (c < 1728) {
            float b = bkvp[c0];
            raw[0][288 + c0] = a0 + b; raw[1][288 + c0] = a1 + b;
        } else {
            float b = bg[c0];
            raw[0][1152 + c0] = 1.0f / (1.0f + expf(-(a0 + b)));
            raw[1][1152 + c0] = 1.0f / (1.0f + expf(-(a1 + b)));
        }
    }
    __syncthreads();

    // point transforms: 192 tasks per row (48 qpts, 48 kpts, 96 vpts)
    for (int idx = tid; idx < BL * 192; idx += 256) {
        int r = idx / 192, t = idx % 192;
        int l = l0 + r;
        const float* R = rot + l * 9;
        float tx = trans[l * 3], ty = trans[l * 3 + 1], tz = trans[l * 3 + 2];
        const float* src; float g = 1.0f; float* dst;
        if (t < 48)      { src = &raw[r][t * 6];            g = raw[r][1152 + t]; dst = qpt + (l * 48 + t) * 6; }
        else if (t < 96) { int j = t - 48; src = &raw[r][288 + j * 6]; dst = kpt + (l * 48 + j) * 6; }
        else             { int j = t - 96; src = &raw[r][576 + j * 6]; dst = vpt + (l * 96 + j) * 6; }
        float px = src[0], py = src[1], pz = src[2], ux = src[3], uy = src[4], uz = src[5];
        float c0 = R[0] * px + R[1] * py + R[2] * pz + tx;
        float c1 = R[3] * px + R[4] * py + R[5] * pz + ty;
        float c2 = R[6] * px + R[7] * py + R[8] * pz + tz;
        float d0 = R[0] * ux + R[1] * uy + R[2] * uz;
        float d1 = R[3] * ux + R[4] * uy + R[5] * uz;
        float d2 = R[6] * ux + R[7] * uy + R[8] * uz;
        dst[0] = c0 * g; dst[1] = c1 * g; dst[2] = c2 * g;
        dst[3] = d0 * g; dst[4] = d1 * g; dst[5] = d2 * g;
    }
}

// ---------------- block reductions over 320 threads (5 waves) ----------------
__device__ inline float blk_max(float v, volatile float* red, int tid) {
    for (int m = 32; m; m >>= 1) v = fmaxf(v, __shfl_xor(v, m, 64));
    if ((tid & 63) == 0) red[tid >> 6] = v;
    __syncthreads();
    float r = red[0];
    #pragma unroll
    for (int i = 1; i < 5; i++) r = fmaxf(r, red[i]);
    __syncthreads();
    return r;
}
__device__ inline float blk_sum(float v, volatile float* red, int tid) {
    for (int m = 32; m; m >>= 1) v += __shfl_xor(v, m, 64);
    if ((tid & 63) == 0) red[tid >> 6] = v;
    __syncthreads();
    float r = red[0];
    #pragma unroll
    for (int i = 1; i < 5; i++) r += red[i];
    __syncthreads();
    return r;
}

// ---------------- kernel 2: attention logits + softmax ----------------
__global__ __launch_bounds__(320) void k_att(
    const float* __restrict__ qb, const float* __restrict__ kb,
    const float* __restrict__ qpt, const float* __restrict__ kpt,
    const float* __restrict__ fm, const float* __restrict__ gw,
    const float* __restrict__ dwp, const float* __restrict__ hwp,
    float* __restrict__ att)
{
    int iq = blockIdx.x, h = blockIdx.y;
    int tid = threadIdx.x;
    __shared__ float qv[CH], qp[PQ * 6], nq[PQ], red[8];

    if (tid < CH) qv[tid] = qb[iq * (NH * CH) + h * CH + tid];
    else if (tid < CH + PQ * 6) { int j = tid - CH; qp[j] = qpt[(iq * NH + h) * PQ * 6 + j]; }
    __syncthreads();
    if (tid < PQ) {
        float x = qp[tid * 6 + 3], y = qp[tid * 6 + 4], zz = qp[tid * 6 + 5];
        nq[tid] = sqrtf(x * x + y * y + zz * zz);
    }
    __syncthreads();

    int kk = tid;
    float kv[CH];
    #pragma unroll
    for (int c = 0; c < CH; c++) kv[c] = kb[kk * (NH * CH) + h * CH + c];
    float kp[PQ * 6];
    #pragma unroll
    for (int j = 0; j < PQ * 6; j++) kp[j] = kpt[(kk * NH + h) * PQ * 6 + j];

    float scalar = 0.f;
    #pragma unroll
    for (int c = 0; c < CH; c++) scalar += qv[c] * kv[c];
    scalar *= 0.25f;  // 1/sqrt(16)

    float pos = 0.f;
    #pragma unroll
    for (int p = 0; p < PQ; p++) {
        float dx = qp[p * 6] - kp[p * 6], dy = qp[p * 6 + 1] - kp[p * 6 + 1], dz = qp[p * 6 + 2] - kp[p * 6 + 2];
        float d = sqrtf(dx * dx + dy * dy + dz * dz);
        pos += d + logf(d + EPSF) + 1.0f / (d + EPSF);
    }
    pos *= 0.25f;

    float nk[PQ];
    #pragma unroll
    for (int p = 0; p < PQ; p++) {
        float x = kp[p * 6 + 3], y = kp[p * 6 + 4], zz = kp[p * 6 + 5];
        nk[p] = sqrtf(x * x + y * y + zz * zz);
    }

    float dir = 0.f;
    #pragma unroll
    for (int p = 0; p < PQ; p++) {  // k-point index
        float kx = kp[p * 6 + 3], ky = kp[p * 6 + 4], kz = kp[p * 6 + 5];
        float cm = 0.f;
        #pragma unroll
        for (int pq = 0; pq < PQ; pq++) {  // q-point index
            float qx = qp[pq * 6 + 3], qy = qp[pq * 6 + 4], qz = qp[pq * 6 + 5];
            float cx = qy * kz - qz * ky;
            float cy = qz * kx - qx * kz;
            float cz = qx * ky - qy * kx;
            cm += sqrtf(cx * cx + cy * cy + cz * cz);
        }
        cm *= 0.25f;
        float qx = qp[p * 6 + 3], qy = qp[p * 6 + 4], qz = qp[p * 6 + 5];
        float dotp = qx * kx + qy * ky + qz * kz;
        dir += dotp - cm / (nq[p] * nk[p] + EPSF);
    }
    dir *= 0.25f;

    float logit = scalar + dwp[0] * (gw[0] * pos + gw[1] * dir);
    logit *= hwp[h];
    logit += 100000.0f * (fm[iq] * fm[kk] - 1.0f);

    float mx = blk_max(logit, red, tid);
    float e = expf(logit - mx);
    float sm = blk_sum(e, red, tid);
    att[(h * LSEQ + iq) * LSEQ + kk] = e / sm;
}

// ---------------- kernel 3: o_scalar / o_geom / o_pair -> concat ----------------
__global__ __launch_bounds__(256) void k_out(
    const float* __restrict__ att, const float* __restrict__ vb,
    const float* __restrict__ vpt, const float* __restrict__ zb,
    const float* __restrict__ rot, const float* __restrict__ trans,
    float* __restrict__ cc)
{
    int iq = blockIdx.x;
    int tid = threadIdx.x;
    __shared__ float a_sh[NH * LSEQ];   // 3840 floats
    __shared__ float og[NH * PV * 6];   // 576 floats

    for (int i = tid; i < NH * LSEQ; i += 256) {
        int h = i / LSEQ, kk = i % LSEQ;
        a_sh[i] = att[(h * LSEQ + iq) * LSEQ + kk];
    }
    __syncthreads();

    // o_scalar: 192 outputs
    if (tid < NH * CH) {
        int h = tid / CH;
        float acc = 0.f;
        for (int kk = 0; kk < LSEQ; kk++) acc += a_sh[h * LSEQ + kk] * vb[kk * (NH * CH) + tid];
        cc[iq * 2400 + tid] = acc;
    }
    // o_geom raw: 576 outputs
    for (int j = tid; j < NH * PV * 6; j += 256) {
        int h = j / (PV * 6);
        float acc = 0.f;
        for (int kk = 0; kk < LSEQ; kk++) acc += a_sh[h * LSEQ + kk] * vpt[kk * (NH * PV * 6) + j];
        og[j] = acc;
    }
    // o_pair: 1536 outputs, 6 heads per thread
    {
        int c = tid & (CZ - 1);
        int h0 = tid >> 7;  // 0 or 1
        float acc[6] = {0, 0, 0, 0, 0, 0};
        const float* zr = zb + (size_t)iq * LSEQ * CZ + c;
        for (int kk = 0; kk < LSEQ; kk++) {
            float zv = zr[(size_t)kk * CZ];
            #pragma unroll
            for (int j = 0; j < 6; j++) acc[j] += a_sh[(h0 + 2 * j) * LSEQ + kk] * zv;
        }
        #pragma unroll
        for (int j = 0; j < 6; j++) cc[iq * 2400 + 864 + (h0 + 2 * j) * CZ + c] = acc[j];
    }
    __syncthreads();

    // inverse-frame transform on o_geom: 96 tasks
    if (tid < NH * PV) {
        int h = tid / PV, p = tid % PV;
        const float* R = rot + iq * 9;
        float tx = trans[iq * 3], ty = trans[iq * 3 + 1], tz = trans[iq * 3 + 2];
        float gx = og[h * 48 + p * 6]     - tx;
        float gy = og[h * 48 + p * 6 + 1] - ty;
        float gz = og[h * 48 + p * 6 + 2] - tz;
        // lc = R^T (o_geom_coords - t)
        float l0 = R[0] * gx + R[3] * gy + R[6] * gz;
        float l1 = R[1] * gx + R[4] * gy + R[7] * gz;
        float l2 = R[2] * gx + R[5] * gy + R[8] * gz;
        float dx = og[h * 48 + p * 6 + 3], dy = og[h * 48 + p * 6 + 4], dz = og[h * 48 + p * 6 + 5];
        float e0 = R[0] * dx + R[3] * dy + R[6] * dz;
        float e1 = R[1] * dx + R[4] * dy + R[7] * dz;
        float e2 = R[2] * dx + R[5] * dy + R[8] * dz;
        float n = sqrtf(e0 * e0 + e1 * e1 + e2 * e2);
        float inv = 1.0f / fmaxf(n, 1e-12f);
        float ln = sqrtf(l0 * l0 + l1 * l1 + l2 * l2);
        float* o = cc + iq * 2400 + NH * CH + (h * PV + p) * 7;
        o[0] = l0; o[1] = l1; o[2] = l2;
        o[3] = e0 * inv; o[4] = e1 * inv; o[5] = e2 * inv;
        o[6] = ln;
    }
}

// ---------------- kernel 4: out = concat @ Wo + bo ----------------
__global__ __launch_bounds__(256) void k_init_out(const float* __restrict__ bo, float* __restrict__ out) {
    int i = blockIdx.x * 256 + threadIdx.x;
    if (i < LSEQ * CS) out[i] = bo[i % CS];
}

__global__ __launch_bounds__(384) void k_gemm(
    const float* __restrict__ cc, const float* __restrict__ Wo, float* __restrict__ out)
{
    const int BQ = 4, KC = 600;
    int q0 = blockIdx.x * BQ;
    int m0 = blockIdx.y * KC;
    int tid = threadIdx.x;  // output column n
    __shared__ float cs[BQ * KC];
    for (int i = tid; i < BQ * KC; i += 384) {
        int r = i / KC, m = i % KC;
        cs[i] = cc[(q0 + r) * 2400 + m0 + m];
    }
    __syncthreads();
    float acc[BQ] = {0, 0, 0, 0};
    for (int m = 0; m < KC; m++) {
        float w = Wo[(size_t)(m0 + m) * CS + tid];
        #pragma unroll
        for (int r = 0; r < BQ; r++) acc[r] += cs[r * KC + m] * w;
    }
    #pragma unroll
    for (int r = 0; r < BQ; r++) atomicAdd(&out[(q0 + r) * CS + tid], acc[r]);
}

extern "C" void kernel_launch(void* const* d_in, const int* in_sizes, int n_in,
                              void* d_out, int out_size, void* d_ws, size_t ws_size,
                              hipStream_t stream)
{
    const float* s     = (const float*)d_in[0];
    const float* rot   = (const float*)d_in[1];
    const float* trans = (const float*)d_in[2];
    const float* z     = (const float*)d_in[3];
    const float* fm    = (const float*)d_in[4];
    const float* Wq    = (const float*)d_in[5];
    const float* bq    = (const float*)d_in[6];
    const float* Wkv   = (const float*)d_in[7];
    const float* bkv   = (const float*)d_in[8];
    const float* Wqp   = (const float*)d_in[9];
    const float* bqp   = (const float*)d_in[10];
    const float* Wkvp  = (const float*)d_in[11];
    const float* bkvp  = (const float*)d_in[12];
    const float* Wg    = (const float*)d_in[13];
    const float* bg    = (const float*)d_in[14];
    const float* gw    = (const float*)d_in[15];
    const float* dw    = (const float*)d_in[16];
    const float* hw    = (const float*)d_in[17];
    const float* Wo    = (const float*)d_in[18];
    const float* bo    = (const float*)d_in[19];

    float* ws  = (float*)d_ws;
    float* q   = ws;
    float* k   = ws + 61440;
    float* v   = ws + 122880;
    float* qpt = ws + 184320;
    float* kpt = ws + 276480;
    float* vpt = ws + 368640;
    float* att = ws + 552960;
    float* cc  = ws + 1781760;
    float* out = (float*)d_out;

    k_proj<<<dim3(LSEQ / 2), dim3(256), 0, stream>>>(s, rot, trans, Wq, bq, Wkv, bkv,
                                                     Wqp, bqp, Wkvp, bkvp, Wg, bg,
                                                     q, k, v, qpt, kpt, vpt);
    k_att<<<dim3(LSEQ, NH), dim3(320), 0, stream>>>(q, k, qpt, kpt, fm, gw, dw, hw, att);
    k_out<<<dim3(LSEQ), dim3(256), 0, stream>>>(att, v, vpt, z, rot, trans, cc);
    k_init_out<<<dim3((LSEQ * CS + 255) / 256), dim3(256), 0, stream>>>(bo, out);
    k_gemm<<<dim3(LSEQ / 4, 4), dim3(384), 0, stream>>>(cc, Wo, out);
}

// Round 2
// 361.775 us; speedup vs baseline: 1.0489x; 1.0489x over previous
//
#include <hip/hip_runtime.h>
#include <hip/hip_bf16.h>
#include <math.h>

#define LSEQ 320
#define CS 384
#define CZ 128
#define CH 16
#define NH 12
#define PQ 4
#define PV 8
#define EPSF 1e-8f

// workspace float offsets (total 2549760 floats = 10.2 MB, same as R1):
// q:    0        (320*192)
// kv:   61440    (320*384)  [k | v]
// qpt:  184320   (320*48*6)   } og (320*576) overlays qpt+kpt after k_att
// kpt:  276480   (320*48*6)   }
// vpt:  368640   (320*96*6)
// att:  552960   (12*320*320) [qpr/kvpr/gate overlay here before k_att]
//   qpr:  552960 (320*288), kvpr: 645120 (320*864), gate: 921600 (320*48)
// cc:   1781760  (320*2400)

// ---------------- kernel 1: fused projection GEMM (320 x 1776 = s @ [Wq|Wkv|Wqp|Wkvp|Wg]) ----
// grid (37 col-tiles of 48, 5 row-tiles of 64); all segment widths divide by 48.
__global__ __launch_bounds__(256) void k_proj(
    const float* __restrict__ s,
    const float* __restrict__ Wq, const float* __restrict__ bq,
    const float* __restrict__ Wkv, const float* __restrict__ bkv,
    const float* __restrict__ Wqp, const float* __restrict__ bqp,
    const float* __restrict__ Wkvp, const float* __restrict__ bkvp,
    const float* __restrict__ Wg, const float* __restrict__ bg,
    float* __restrict__ qo, float* __restrict__ kvo,
    float* __restrict__ qpr, float* __restrict__ kvpr, float* __restrict__ gate)
{
    __shared__ float a_sh[64][33];   // [row][k] +1 pad
    __shared__ float w_sh[32][48];   // [k][col]
    int ct = blockIdx.x, l0 = blockIdx.y * 64;
    int tid = threadIdx.x;
    int col0 = ct * 48;
    const float *W, *bias; float* dst; int nc, cbase; bool sig = false;
    if (col0 < 192)       { W = Wq;   bias = bq;   nc = 192; cbase = col0;        dst = qo;   }
    else if (col0 < 576)  { W = Wkv;  bias = bkv;  nc = 384; cbase = col0 - 192;  dst = kvo;  }
    else if (col0 < 864)  { W = Wqp;  bias = bqp;  nc = 288; cbase = col0 - 576;  dst = qpr;  }
    else if (col0 < 1728) { W = Wkvp; bias = bkvp; nc = 864; cbase = col0 - 864;  dst = kvpr; }
    else                  { W = Wg;   bias = bg;   nc = 48;  cbase = 0;           dst = gate; sig = true; }

    int tx = tid & 15, ty = tid >> 4;   // thread computes 4 rows x 3 cols
    float acc[4][3] = {};
    for (int k0 = 0; k0 < CS; k0 += 32) {
        __syncthreads();
        {
            int kk = tid & 31, r0 = tid >> 5;
            #pragma unroll
            for (int rr = 0; rr < 8; rr++) {
                int r = r0 * 8 + rr;
                a_sh[r][kk] = s[(size_t)(l0 + r) * CS + k0 + kk];
            }
        }
        for (int idx = tid; idx < 32 * 48; idx += 256) {
            int kk = idx / 48, c = idx % 48;
            w_sh[kk][c] = W[(size_t)(k0 + kk) * nc + cbase + c];
        }
        __syncthreads();
        #pragma unroll 8
        for (int kk = 0; kk < 32; kk++) {
            float b0 = w_sh[kk][tx * 3], b1 = w_sh[kk][tx * 3 + 1], b2 = w_sh[kk][tx * 3 + 2];
            #pragma unroll
            for (int rr = 0; rr < 4; rr++) {
                float a = a_sh[ty * 4 + rr][kk];
                acc[rr][0] += a * b0; acc[rr][1] += a * b1; acc[rr][2] += a * b2;
            }
        }
    }
    #pragma unroll
    for (int i = 0; i < 3; i++) {
        int c = cbase + tx * 3 + i;
        float bv = bias[c];
        #pragma unroll
        for (int rr = 0; rr < 4; rr++) {
            float v = acc[rr][i] + bv;
            if (sig) v = 1.0f / (1.0f + expf(-v));
            dst[(size_t)(l0 + ty * 4 + rr) * nc + c] = v;
        }
    }
}

// ---------------- kernel 2: frame transforms + gate ----------------
__global__ __launch_bounds__(192) void k_points(
    const float* __restrict__ qpr, const float* __restrict__ kvpr, const float* __restrict__ gate,
    const float* __restrict__ rot, const float* __restrict__ trans,
    float* __restrict__ qpt, float* __restrict__ kpt, float* __restrict__ vpt)
{
    int l = blockIdx.x, t = threadIdx.x;
    const float* R = rot + l * 9;
    float tx = trans[l * 3], ty = trans[l * 3 + 1], tz = trans[l * 3 + 2];
    const float* src; float g = 1.0f; float* dst;
    if (t < 48)      { src = qpr + (size_t)l * 288 + t * 6; g = gate[l * 48 + t]; dst = qpt + ((size_t)l * 48 + t) * 6; }
    else if (t < 96) { int j = t - 48; src = kvpr + (size_t)l * 864 + j * 6; dst = kpt + ((size_t)l * 48 + j) * 6; }
    else             { int j = t - 96; src = kvpr + (size_t)l * 864 + 288 + j * 6; dst = vpt + ((size_t)l * 96 + j) * 6; }
    float px = src[0], py = src[1], pz = src[2], ux = src[3], uy = src[4], uz = src[5];
    float c0 = R[0] * px + R[1] * py + R[2] * pz + tx;
    float c1 = R[3] * px + R[4] * py + R[5] * pz + ty;
    float c2 = R[6] * px + R[7] * py + R[8] * pz + tz;
    float d0 = R[0] * ux + R[1] * uy + R[2] * uz;
    float d1 = R[3] * ux + R[4] * uy + R[5] * uz;
    float d2 = R[6] * ux + R[7] * uy + R[8] * uz;
    dst[0] = c0 * g; dst[1] = c1 * g; dst[2] = c2 * g;
    dst[3] = d0 * g; dst[4] = d1 * g; dst[5] = d2 * g;
}

// ---------------- block reductions over 320 threads (5 waves) ----------------
__device__ inline float blk_max(float v, volatile float* red, int tid) {
    for (int m = 32; m; m >>= 1) v = fmaxf(v, __shfl_xor(v, m, 64));
    if ((tid & 63) == 0) red[tid >> 6] = v;
    __syncthreads();
    float r = red[0];
    #pragma unroll
    for (int i = 1; i < 5; i++) r = fmaxf(r, red[i]);
    __syncthreads();
    return r;
}
__device__ inline float blk_sum(float v, volatile float* red, int tid) {
    for (int m = 32; m; m >>= 1) v += __shfl_xor(v, m, 64);
    if ((tid & 63) == 0) red[tid >> 6] = v;
    __syncthreads();
    float r = red[0];
    #pragma unroll
    for (int i = 1; i < 5; i++) r += red[i];
    __syncthreads();
    return r;
}

// ---------------- kernel 3: attention logits + softmax ----------------
__global__ __launch_bounds__(320) void k_att(
    const float* __restrict__ qb, const float* __restrict__ kvb,
    const float* __restrict__ qpt, const float* __restrict__ kpt,
    const float* __restrict__ fm, const float* __restrict__ gw,
    const float* __restrict__ dwp, const float* __restrict__ hwp,
    float* __restrict__ att)
{
    int iq = blockIdx.x, h = blockIdx.y;
    int tid = threadIdx.x;
    __shared__ float qv[CH], qp[PQ * 6], nq[PQ], red[8];

    if (tid < CH) qv[tid] = qb[(size_t)iq * (NH * CH) + h * CH + tid];
    else if (tid < CH + PQ * 6) { int j = tid - CH; qp[j] = qpt[((size_t)iq * NH + h) * PQ * 6 + j]; }
    __syncthreads();
    if (tid < PQ) {
        float x = qp[tid * 6 + 3], y = qp[tid * 6 + 4], zz = qp[tid * 6 + 5];
        nq[tid] = sqrtf(x * x + y * y + zz * zz);
    }
    __syncthreads();

    int kk = tid;
    float kv[CH];
    #pragma unroll
    for (int c = 0; c < CH; c++) kv[c] = kvb[(size_t)kk * 384 + h * CH + c];
    float kp[PQ * 6];
    #pragma unroll
    for (int j = 0; j < PQ * 6; j++) kp[j] = kpt[((size_t)kk * NH + h) * PQ * 6 + j];

    float scalar = 0.f;
    #pragma unroll
    for (int c = 0; c < CH; c++) scalar += qv[c] * kv[c];
    scalar *= 0.25f;

    float pos = 0.f;
    #pragma unroll
    for (int p = 0; p < PQ; p++) {
        float dx = qp[p * 6] - kp[p * 6], dy = qp[p * 6 + 1] - kp[p * 6 + 1], dz = qp[p * 6 + 2] - kp[p * 6 + 2];
        float d = sqrtf(dx * dx + dy * dy + dz * dz);
        pos += d + logf(d + EPSF) + 1.0f / (d + EPSF);
    }
    pos *= 0.25f;

    float nk[PQ];
    #pragma unroll
    for (int p = 0; p < PQ; p++) {
        float x = kp[p * 6 + 3], y = kp[p * 6 + 4], zz = kp[p * 6 + 5];
        nk[p] = sqrtf(x * x + y * y + zz * zz);
    }

    float dir = 0.f;
    #pragma unroll
    for (int p = 0; p < PQ; p++) {
        float kx = kp[p * 6 + 3], ky = kp[p * 6 + 4], kz = kp[p * 6 + 5];
        float cm = 0.f;
        #pragma unroll
        for (int pq = 0; pq < PQ; pq++) {
            float qx = qp[pq * 6 + 3], qy = qp[pq * 6 + 4], qz = qp[pq * 6 + 5];
            float cx = qy * kz - qz * ky;
            float cy = qz * kx - qx * kz;
            float cz = qx * ky - qy * kx;
            cm += sqrtf(cx * cx + cy * cy + cz * cz);
        }
        cm *= 0.25f;
        float qx = qp[p * 6 + 3], qy = qp[p * 6 + 4], qz = qp[p * 6 + 5];
        float dotp = qx * kx + qy * ky + qz * kz;
        dir += dotp - cm / (nq[p] * nk[p] + EPSF);
    }
    dir *= 0.25f;

    float logit = scalar + dwp[0] * (gw[0] * pos + gw[1] * dir);
    logit *= hwp[h];
    logit += 100000.0f * (fm[iq] * fm[kk] - 1.0f);

    float mx = blk_max(logit, red, tid);
    float e = expf(logit - mx);
    float sm = blk_sum(e, red, tid);
    att[((size_t)h * LSEQ + iq) * LSEQ + kk] = e / sm;
}

// ---------------- kernel 4: init out with bias, zero cc pair region ----------------
__global__ __launch_bounds__(256) void k_initzero(
    const float* __restrict__ bo, float* __restrict__ out, float* __restrict__ cc)
{
    int i = blockIdx.x * 256 + threadIdx.x;
    if (i < LSEQ * CS) out[i] = bo[i % CS];
    else {
        int j = i - LSEQ * CS;              // < 320*1536
        int iq = j / 1536, t = j % 1536;
        cc[(size_t)iq * 2400 + 864 + t] = 0.0f;
    }
}

// ---------------- kernel 5: o_scalar + o_geom as batched GEMM (per-h) ----------------
// grid (5 row-tiles, 12 heads). C tile: 64 iq x 64 cols (16 scalar | 48 geom-raw).
__global__ __launch_bounds__(256) void k_sv(
    const float* __restrict__ att, const float* __restrict__ kvb,
    const float* __restrict__ vpt, float* __restrict__ cc, float* __restrict__ og)
{
    __shared__ float a_sh[64][33];
    __shared__ float v_sh[32][64];
    int iq0 = blockIdx.x * 64, h = blockIdx.y;
    int tid = threadIdx.x;
    int tx = tid & 15, ty = tid >> 4;   // 4 rows x 4 cols each
    float acc[4][4] = {};
    for (int k0 = 0; k0 < LSEQ; k0 += 32) {
        __syncthreads();
        {
            int kk = tid & 31, r0 = tid >> 5;
            #pragma unroll
            for (int rr = 0; rr < 8; rr++) {
                int r = r0 * 8 + rr;
                a_sh[r][kk] = att[((size_t)h * LSEQ + iq0 + r) * LSEQ + k0 + kk];
            }
        }
        for (int idx = tid; idx < 32 * 64; idx += 256) {
            int kk = idx >> 6, c = idx & 63;
            float v;
            if (c < 16) v = kvb[(size_t)(k0 + kk) * 384 + 192 + h * 16 + c];
            else        v = vpt[(size_t)((k0 + kk) * 96 + h * 8) * 6 + (c - 16)];
            v_sh[kk][c] = v;
        }
        __syncthreads();
        #pragma unroll 8
        for (int kk = 0; kk < 32; kk++) {
            float b0 = v_sh[kk][tx * 4], b1 = v_sh[kk][tx * 4 + 1];
            float b2 = v_sh[kk][tx * 4 + 2], b3 = v_sh[kk][tx * 4 + 3];
            #pragma unroll
            for (int rr = 0; rr < 4; rr++) {
                float a = a_sh[ty * 4 + rr][kk];
                acc[rr][0] += a * b0; acc[rr][1] += a * b1;
                acc[rr][2] += a * b2; acc[rr][3] += a * b3;
            }
        }
    }
    #pragma unroll
    for (int rr = 0; rr < 4; rr++) {
        int iq = iq0 + ty * 4 + rr;
        #pragma unroll
        for (int j = 0; j < 4; j++) {
            int c = tx * 4 + j;
            if (c < 16) cc[(size_t)iq * 2400 + h * 16 + c] = acc[rr][j];
            else        og[(size_t)iq * 576 + h * 48 + (c - 16)] = acc[rr][j];
        }
    }
}

// ---------------- kernel 6: o_pair, split-k with atomics ----------------
__global__ __launch_bounds__(256) void k_pair(
    const float* __restrict__ att, const float* __restrict__ z, float* __restrict__ cc)
{
    int iq = blockIdx.x, kk0 = blockIdx.y * 64;
    int tid = threadIdx.x;
    __shared__ float a_sh[NH][64];
    for (int idx = tid; idx < NH * 64; idx += 256) {
        int h = idx >> 6, j = idx & 63;
        a_sh[h][j] = att[((size_t)h * LSEQ + iq) * LSEQ + kk0 + j];
    }
    __syncthreads();
    int c = tid & 127, h0 = tid >> 7;   // h = h0 + 2j
    float acc[6] = {};
    const float* zr = z + ((size_t)iq * LSEQ + kk0) * CZ + c;
    #pragma unroll 4
    for (int kk = 0; kk < 64; kk++) {
        float zv = zr[(size_t)kk * CZ];
        #pragma unroll
        for (int j = 0; j < 6; j++) acc[j] += a_sh[h0 + 2 * j][kk] * zv;
    }
    #pragma unroll
    for (int j = 0; j < 6; j++)
        atomicAdd(&cc[(size_t)iq * 2400 + 864 + (h0 + 2 * j) * CZ + c], acc[j]);
}

// ---------------- kernel 7: inverse-frame transform on o_geom ----------------
__global__ __launch_bounds__(128) void k_finish(
    const float* __restrict__ og, const float* __restrict__ rot, const float* __restrict__ trans,
    float* __restrict__ cc)
{
    int iq = blockIdx.x, tid = threadIdx.x;
    if (tid >= NH * PV) return;
    int h = tid / PV, p = tid % PV;
    const float* R = rot + iq * 9;
    float tx = trans[iq * 3], ty = trans[iq * 3 + 1], tz = trans[iq * 3 + 2];
    const float* o = og + (size_t)iq * 576 + h * 48 + p * 6;
    float gx = o[0] - tx, gy = o[1] - ty, gz = o[2] - tz;
    float l0 = R[0] * gx + R[3] * gy + R[6] * gz;
    float l1 = R[1] * gx + R[4] * gy + R[7] * gz;
    float l2 = R[2] * gx + R[5] * gy + R[8] * gz;
    float dx = o[3], dy = o[4], dz = o[5];
    float e0 = R[0] * dx + R[3] * dy + R[6] * dz;
    float e1 = R[1] * dx + R[4] * dy + R[7] * dz;
    float e2 = R[2] * dx + R[5] * dy + R[8] * dz;
    float n = sqrtf(e0 * e0 + e1 * e1 + e2 * e2);
    float inv = 1.0f / fmaxf(n, 1e-12f);
    float ln = sqrtf(l0 * l0 + l1 * l1 + l2 * l2);
    float* oc = cc + (size_t)iq * 2400 + NH * CH + (h * PV + p) * 7;
    oc[0] = l0; oc[1] = l1; oc[2] = l2;
    oc[3] = e0 * inv; oc[4] = e1 * inv; oc[5] = e2 * inv;
    oc[6] = ln;
}

// ---------------- kernel 8: out += concat @ Wo, tiled split-K ----------------
// grid (5 row-tiles x 3 col-tiles x 10 k-splits of 240)
__global__ __launch_bounds__(256) void k_gemm(
    const float* __restrict__ cc, const float* __restrict__ Wo, float* __restrict__ out)
{
    __shared__ float a_sh[64][17];
    __shared__ float w_sh[16][128];
    int iq0 = blockIdx.x * 64, cn0 = blockIdx.y * 128, ks = blockIdx.z;
    int tid = threadIdx.x;
    int tx = tid & 15, ty = tid >> 4;   // 4 rows x 8 cols (col = tx + j*16)
    float acc[4][8] = {};
    for (int k0 = ks * 240; k0 < ks * 240 + 240; k0 += 16) {
        __syncthreads();
        {
            int kk = tid & 15, r0 = tid >> 4;
            #pragma unroll
            for (int rr = 0; rr < 4; rr++) {
                int r = r0 * 4 + rr;
                a_sh[r][kk] = cc[(size_t)(iq0 + r) * 2400 + k0 + kk];
            }
        }
        for (int idx = tid; idx < 16 * 128; idx += 256) {
            int kk = idx >> 7, c2 = idx & 127;
            w_sh[kk][c2] = Wo[(size_t)(k0 + kk) * CS + cn0 + c2];
        }
        __syncthreads();
        #pragma unroll
        for (int kk = 0; kk < 16; kk++) {
            float b[8];
            #pragma unroll
            for (int j = 0; j < 8; j++) b[j] = w_sh[kk][tx + j * 16];
            #pragma unroll
            for (int rr = 0; rr < 4; rr++) {
                float a = a_sh[ty * 4 + rr][kk];
                #pragma unroll
                for (int j = 0; j < 8; j++) acc[rr][j] += a * b[j];
            }
        }
    }
    #pragma unroll
    for (int rr = 0; rr < 4; rr++) {
        int row = iq0 + ty * 4 + rr;
        #pragma unroll
        for (int j = 0; j < 8; j++)
            atomicAdd(&out[(size_t)row * CS + cn0 + tx + j * 16], acc[rr][j]);
    }
}

extern "C" void kernel_launch(void* const* d_in, const int* in_sizes, int n_in,
                              void* d_out, int out_size, void* d_ws, size_t ws_size,
                              hipStream_t stream)
{
    const float* s     = (const float*)d_in[0];
    const float* rot   = (const float*)d_in[1];
    const float* trans = (const float*)d_in[2];
    const float* z     = (const float*)d_in[3];
    const float* fm    = (const float*)d_in[4];
    const float* Wq    = (const float*)d_in[5];
    const float* bq    = (const float*)d_in[6];
    const float* Wkv   = (const float*)d_in[7];
    const float* bkv   = (const float*)d_in[8];
    const float* Wqp   = (const float*)d_in[9];
    const float* bqp   = (const float*)d_in[10];
    const float* Wkvp  = (const float*)d_in[11];
    const float* bkvp  = (const float*)d_in[12];
    const float* Wg    = (const float*)d_in[13];
    const float* bg    = (const float*)d_in[14];
    const float* gw    = (const float*)d_in[15];
    const float* dw    = (const float*)d_in[16];
    const float* hw    = (const float*)d_in[17];
    const float* Wo    = (const float*)d_in[18];
    const float* bo    = (const float*)d_in[19];

    float* ws   = (float*)d_ws;
    float* q    = ws;
    float* kv   = ws + 61440;
    float* qpt  = ws + 184320;
    float* kpt  = ws + 276480;
    float* vpt  = ws + 368640;
    float* att  = ws + 552960;
    float* qpr  = ws + 552960;   // overlays att (dead before k_att writes)
    float* kvpr = ws + 645120;
    float* gate = ws + 921600;
    float* og   = ws + 184320;   // overlays qpt/kpt (dead after k_att)
    float* cc   = ws + 1781760;
    float* out  = (float*)d_out;

    k_proj<<<dim3(37, 5), dim3(256), 0, stream>>>(s, Wq, bq, Wkv, bkv, Wqp, bqp,
                                                  Wkvp, bkvp, Wg, bg,
                                                  q, kv, qpr, kvpr, gate);
    k_points<<<dim3(LSEQ), dim3(192), 0, stream>>>(qpr, kvpr, gate, rot, trans, qpt, kpt, vpt);
    k_att<<<dim3(LSEQ, NH), dim3(320), 0, stream>>>(q, kv, qpt, kpt, fm, gw, dw, hw, att);
    k_initzero<<<dim3((LSEQ * CS + LSEQ * 1536) / 256), dim3(256), 0, stream>>>(bo, out, cc);
    k_sv<<<dim3(5, NH), dim3(256), 0, stream>>>(att, kv, vpt, cc, og);
    k_pair<<<dim3(LSEQ, 5), dim3(256), 0, stream>>>(att, z, cc);
    k_finish<<<dim3(LSEQ), dim3(128), 0, stream>>>(og, rot, trans, cc);
    k_gemm<<<dim3(5, 3, 10), dim3(256), 0, stream>>>(cc, Wo, out);
}

// Round 3
// 262.655 us; speedup vs baseline: 1.4447x; 1.3774x over previous
//
#include <hip/hip_runtime.h>
#include <hip/hip_bf16.h>
#include <math.h>

#define LSEQ 320
#define CS 384
#define CZ 128
#define CH 16
#define NH 12
#define PQ 4
#define PV 8
#define EPSF 1e-8f

// workspace float offsets (total 2549760 floats = 10.2 MB):
// q:    0        (320*192)
// kv:   61440    (320*384)  [k | v]
// qpt:  184320   (320*48*6)   } og (320*576) overlays qpt+kpt after k_att
// kpt:  276480   (320*48*6)   }
// vpt:  368640   (320*96*6)
// att:  552960   (12*320*320) [qpr/kvpr/gate overlay here before k_att]
//   qpr:  552960 (320*288), kvpr: 645120 (320*864), gate: 921600 (320*48)
// cc:   1781760  (320*2400)

// ---------------- kernel 1: fused projection GEMM (320 x 1776) ----------------
// grid (37 col-tiles of 48, 20 row-tiles of 16) = 740 blocks
__global__ __launch_bounds__(256) void k_proj(
    const float* __restrict__ s,
    const float* __restrict__ Wq, const float* __restrict__ bq,
    const float* __restrict__ Wkv, const float* __restrict__ bkv,
    const float* __restrict__ Wqp, const float* __restrict__ bqp,
    const float* __restrict__ Wkvp, const float* __restrict__ bkvp,
    const float* __restrict__ Wg, const float* __restrict__ bg,
    float* __restrict__ qo, float* __restrict__ kvo,
    float* __restrict__ qpr, float* __restrict__ kvpr, float* __restrict__ gate)
{
    __shared__ float a_sh[16][33];
    __shared__ float w_sh[32][48];
    int col0 = blockIdx.x * 48, l0 = blockIdx.y * 16;
    int tid = threadIdx.x;
    const float *W, *bias; float* dst; int nc, cbase; bool sig = false;
    if (col0 < 192)       { W = Wq;   bias = bq;   nc = 192; cbase = col0;        dst = qo;   }
    else if (col0 < 576)  { W = Wkv;  bias = bkv;  nc = 384; cbase = col0 - 192;  dst = kvo;  }
    else if (col0 < 864)  { W = Wqp;  bias = bqp;  nc = 288; cbase = col0 - 576;  dst = qpr;  }
    else if (col0 < 1728) { W = Wkvp; bias = bkvp; nc = 864; cbase = col0 - 864;  dst = kvpr; }
    else                  { W = Wg;   bias = bg;   nc = 48;  cbase = 0;           dst = gate; sig = true; }

    int tx = tid & 15, ty = tid >> 4;   // thread: 1 row (ty), 3 cols (tx*3..)
    float acc[3] = {};
    for (int k0 = 0; k0 < CS; k0 += 32) {
        __syncthreads();
        #pragma unroll
        for (int t = 0; t < 2; t++) {
            int idx = tid + t * 256;
            a_sh[idx >> 5][idx & 31] = s[(size_t)(l0 + (idx >> 5)) * CS + k0 + (idx & 31)];
        }
        #pragma unroll
        for (int idx = tid; idx < 32 * 48; idx += 256) {
            int kk = idx / 48, c = idx - kk * 48;
            w_sh[kk][c] = W[(size_t)(k0 + kk) * nc + cbase + c];
        }
        __syncthreads();
        #pragma unroll 8
        for (int kk = 0; kk < 32; kk++) {
            float a = a_sh[ty][kk];
            acc[0] += a * w_sh[kk][tx * 3];
            acc[1] += a * w_sh[kk][tx * 3 + 1];
            acc[2] += a * w_sh[kk][tx * 3 + 2];
        }
    }
    #pragma unroll
    for (int i = 0; i < 3; i++) {
        int c = cbase + tx * 3 + i;
        float v = acc[i] + bias[c];
        if (sig) v = 1.0f / (1.0f + expf(-v));
        dst[(size_t)(l0 + ty) * nc + c] = v;
    }
}

// ---------------- kernel 2: frame transforms + gate ----------------
__global__ __launch_bounds__(192) void k_points(
    const float* __restrict__ qpr, const float* __restrict__ kvpr, const float* __restrict__ gate,
    const float* __restrict__ rot, const float* __restrict__ trans,
    float* __restrict__ qpt, float* __restrict__ kpt, float* __restrict__ vpt)
{
    int l = blockIdx.x, t = threadIdx.x;
    const float* R = rot + l * 9;
    float tx = trans[l * 3], ty = trans[l * 3 + 1], tz = trans[l * 3 + 2];
    const float* src; float g = 1.0f; float* dst;
    if (t < 48)      { src = qpr + (size_t)l * 288 + t * 6; g = gate[l * 48 + t]; dst = qpt + ((size_t)l * 48 + t) * 6; }
    else if (t < 96) { int j = t - 48; src = kvpr + (size_t)l * 864 + j * 6; dst = kpt + ((size_t)l * 48 + j) * 6; }
    else             { int j = t - 96; src = kvpr + (size_t)l * 864 + 288 + j * 6; dst = vpt + ((size_t)l * 96 + j) * 6; }
    float px = src[0], py = src[1], pz = src[2], ux = src[3], uy = src[4], uz = src[5];
    float c0 = R[0] * px + R[1] * py + R[2] * pz + tx;
    float c1 = R[3] * px + R[4] * py + R[5] * pz + ty;
    float c2 = R[6] * px + R[7] * py + R[8] * pz + tz;
    float d0 = R[0] * ux + R[1] * uy + R[2] * uz;
    float d1 = R[3] * ux + R[4] * uy + R[5] * uz;
    float d2 = R[6] * ux + R[7] * uy + R[8] * uz;
    dst[0] = c0 * g; dst[1] = c1 * g; dst[2] = c2 * g;
    dst[3] = d0 * g; dst[4] = d1 * g; dst[5] = d2 * g;
}

// ---------------- kernel 3: attention logits + softmax, 1 wave per (iq,h) ----------------
// grid (80, 12), block 256 = 4 waves; no LDS, no __syncthreads.
__global__ __launch_bounds__(256) void k_att(
    const float* __restrict__ qb, const float* __restrict__ kvb,
    const float* __restrict__ qpt, const float* __restrict__ kpt,
    const float* __restrict__ fm, const float* __restrict__ gw,
    const float* __restrict__ dwp, const float* __restrict__ hwp,
    float* __restrict__ att)
{
    int w = threadIdx.x >> 6, lane = threadIdx.x & 63;
    int iq = blockIdx.x * 4 + w;
    int h = blockIdx.y;

    float qv[CH];
    #pragma unroll
    for (int c = 0; c < CH; c++) qv[c] = qb[(size_t)iq * (NH * CH) + h * CH + c];
    float qp[PQ * 6];
    #pragma unroll
    for (int j = 0; j < PQ * 6; j++) qp[j] = qpt[((size_t)iq * NH + h) * PQ * 6 + j];
    float nq[PQ];
    #pragma unroll
    for (int p = 0; p < PQ; p++) {
        float x = qp[p * 6 + 3], y = qp[p * 6 + 4], zz = qp[p * 6 + 5];
        nq[p] = sqrtf(x * x + y * y + zz * zz);
    }
    float dwv = dwp[0], g0 = gw[0], g1 = gw[1], hwv = hwp[h];
    float fmi = fm[iq];

    float lg[5];
    #pragma unroll
    for (int r = 0; r < 5; r++) {
        int kk = r * 64 + lane;
        float kp[PQ * 6];
        #pragma unroll
        for (int j = 0; j < PQ * 6; j++) kp[j] = kpt[((size_t)kk * NH + h) * PQ * 6 + j];

        float scalar = 0.f;
        #pragma unroll
        for (int c = 0; c < CH; c++) scalar += qv[c] * kvb[(size_t)kk * 384 + h * CH + c];
        scalar *= 0.25f;

        float pos = 0.f;
        #pragma unroll
        for (int p = 0; p < PQ; p++) {
            float dx = qp[p * 6] - kp[p * 6], dy = qp[p * 6 + 1] - kp[p * 6 + 1], dz = qp[p * 6 + 2] - kp[p * 6 + 2];
            float d = sqrtf(dx * dx + dy * dy + dz * dz);
            pos += d + logf(d + EPSF) + 1.0f / (d + EPSF);
        }
        pos *= 0.25f;

        float dir = 0.f;
        #pragma unroll
        for (int p = 0; p < PQ; p++) {
            float kx = kp[p * 6 + 3], ky = kp[p * 6 + 4], kz = kp[p * 6 + 5];
            float nk = sqrtf(kx * kx + ky * ky + kz * kz);
            float cm = 0.f;
            #pragma unroll
            for (int pq = 0; pq < PQ; pq++) {
                float qx = qp[pq * 6 + 3], qy = qp[pq * 6 + 4], qz = qp[pq * 6 + 5];
                float cx = qy * kz - qz * ky;
                float cy = qz * kx - qx * kz;
                float cz = qx * ky - qy * kx;
                cm += sqrtf(cx * cx + cy * cy + cz * cz);
            }
            cm *= 0.25f;
            float qx = qp[p * 6 + 3], qy = qp[p * 6 + 4], qz = qp[p * 6 + 5];
            float dotp = qx * kx + qy * ky + qz * kz;
            dir += dotp - cm / (nq[p] * nk + EPSF);
        }
        dir *= 0.25f;

        float logit = scalar + dwv * (g0 * pos + g1 * dir);
        logit *= hwv;
        logit += 100000.0f * (fmi * fm[kk] - 1.0f);
        lg[r] = logit;
    }

    float mx = lg[0];
    #pragma unroll
    for (int r = 1; r < 5; r++) mx = fmaxf(mx, lg[r]);
    for (int m = 32; m; m >>= 1) mx = fmaxf(mx, __shfl_xor(mx, m, 64));

    float e[5], sm = 0.f;
    #pragma unroll
    for (int r = 0; r < 5; r++) { e[r] = expf(lg[r] - mx); sm += e[r]; }
    for (int m = 32; m; m >>= 1) sm += __shfl_xor(sm, m, 64);
    float inv = 1.0f / sm;
    #pragma unroll
    for (int r = 0; r < 5; r++)
        att[((size_t)h * LSEQ + iq) * LSEQ + r * 64 + lane] = e[r] * inv;
}

// ---------------- kernel 4: init out with bias, zero cc + og ----------------
// total = 768000 (cc) + 184320 (og) + 122880 (out) = 1075200 = 4200 blocks
__global__ __launch_bounds__(256) void k_initzero(
    const float* __restrict__ bo, float* __restrict__ out,
    float* __restrict__ cc, float* __restrict__ og)
{
    int i = blockIdx.x * 256 + threadIdx.x;
    if (i < 768000) cc[i] = 0.0f;
    else if (i < 952320) og[i - 768000] = 0.0f;
    else { int j = i - 952320; out[j] = bo[j % CS]; }
}

// ---------------- kernel 5: o_scalar + o_geom, split-K atomic ----------------
// grid (20 iq-tiles of 16, 12 heads, 4 k-splits of 80) = 960 blocks
__global__ __launch_bounds__(256) void k_sv(
    const float* __restrict__ att, const float* __restrict__ kvb,
    const float* __restrict__ vpt, float* __restrict__ cc, float* __restrict__ og)
{
    __shared__ float a_sh[16][17];
    __shared__ float v_sh[16][64];
    int iq0 = blockIdx.x * 16, h = blockIdx.y, ks = blockIdx.z;
    int tid = threadIdx.x;
    int tx = tid & 15, ty = tid >> 4;   // 1 row x 4 cols
    float acc[4] = {};
    for (int kc = 0; kc < 5; kc++) {
        int k0 = ks * 80 + kc * 16;
        __syncthreads();
        {
            int row = tid >> 4, kk = tid & 15;
            a_sh[row][kk] = att[((size_t)h * LSEQ + iq0 + row) * LSEQ + k0 + kk];
        }
        #pragma unroll
        for (int t = 0; t < 4; t++) {
            int idx = tid + t * 256;
            int kk = idx >> 6, c = idx & 63;
            float v;
            if (c < 16) v = kvb[(size_t)(k0 + kk) * 384 + 192 + h * 16 + c];
            else        v = vpt[(size_t)((k0 + kk) * 96 + h * 8) * 6 + (c - 16)];
            v_sh[kk][c] = v;
        }
        __syncthreads();
        #pragma unroll
        for (int kk = 0; kk < 16; kk++) {
            float a = a_sh[ty][kk];
            float4 b = *(const float4*)&v_sh[kk][tx * 4];
            acc[0] += a * b.x; acc[1] += a * b.y; acc[2] += a * b.z; acc[3] += a * b.w;
        }
    }
    int iq = iq0 + ty;
    #pragma unroll
    for (int i = 0; i < 4; i++) {
        int c = tx * 4 + i;
        if (c < 16) atomicAdd(&cc[(size_t)iq * 2400 + h * 16 + c], acc[i]);
        else        atomicAdd(&og[(size_t)iq * 576 + h * 48 + (c - 16)], acc[i]);
    }
}

// ---------------- kernel 6: o_pair, split-k with atomics ----------------
__global__ __launch_bounds__(256) void k_pair(
    const float* __restrict__ att, const float* __restrict__ z, float* __restrict__ cc)
{
    int iq = blockIdx.x, kk0 = blockIdx.y * 64;
    int tid = threadIdx.x;
    __shared__ float a_sh[NH][64];
    for (int idx = tid; idx < NH * 64; idx += 256) {
        int h = idx >> 6, j = idx & 63;
        a_sh[h][j] = att[((size_t)h * LSEQ + iq) * LSEQ + kk0 + j];
    }
    __syncthreads();
    int c = tid & 127, h0 = tid >> 7;   // h = h0 + 2j
    float acc[6] = {};
    const float* zr = z + ((size_t)iq * LSEQ + kk0) * CZ + c;
    #pragma unroll 4
    for (int kk = 0; kk < 64; kk++) {
        float zv = zr[(size_t)kk * CZ];
        #pragma unroll
        for (int j = 0; j < 6; j++) acc[j] += a_sh[h0 + 2 * j][kk] * zv;
    }
    #pragma unroll
    for (int j = 0; j < 6; j++)
        atomicAdd(&cc[(size_t)iq * 2400 + 864 + (h0 + 2 * j) * CZ + c], acc[j]);
}

// ---------------- kernel 7: inverse-frame transform on o_geom ----------------
__global__ __launch_bounds__(128) void k_finish(
    const float* __restrict__ og, const float* __restrict__ rot, const float* __restrict__ trans,
    float* __restrict__ cc)
{
    int iq = blockIdx.x, tid = threadIdx.x;
    if (tid >= NH * PV) return;
    int h = tid / PV, p = tid % PV;
    const float* R = rot + iq * 9;
    float tx = trans[iq * 3], ty = trans[iq * 3 + 1], tz = trans[iq * 3 + 2];
    const float* o = og + (size_t)iq * 576 + h * 48 + p * 6;
    float gx = o[0] - tx, gy = o[1] - ty, gz = o[2] - tz;
    float l0 = R[0] * gx + R[3] * gy + R[6] * gz;
    float l1 = R[1] * gx + R[4] * gy + R[7] * gz;
    float l2 = R[2] * gx + R[5] * gy + R[8] * gz;
    float dx = o[3], dy = o[4], dz = o[5];
    float e0 = R[0] * dx + R[3] * dy + R[6] * dz;
    float e1 = R[1] * dx + R[4] * dy + R[7] * dz;
    float e2 = R[2] * dx + R[5] * dy + R[8] * dz;
    float n = sqrtf(e0 * e0 + e1 * e1 + e2 * e2);
    float inv = 1.0f / fmaxf(n, 1e-12f);
    float ln = sqrtf(l0 * l0 + l1 * l1 + l2 * l2);
    float* oc = cc + (size_t)iq * 2400 + NH * CH + (h * PV + p) * 7;
    oc[0] = l0; oc[1] = l1; oc[2] = l2;
    oc[3] = e0 * inv; oc[4] = e1 * inv; oc[5] = e2 * inv;
    oc[6] = ln;
}

// ---------------- kernel 8: out += concat @ Wo, fine split-K ----------------
// grid (20 row-tiles of 16, 6 col-tiles of 64, 10 k-splits of 240) = 1200 blocks
__global__ __launch_bounds__(256) void k_gemm(
    const float* __restrict__ cc, const float* __restrict__ Wo, float* __restrict__ out)
{
    __shared__ float a_sh[16][17];
    __shared__ float w_sh[16][64];
    int iq0 = blockIdx.x * 16, cn0 = blockIdx.y * 64, ks = blockIdx.z;
    int tid = threadIdx.x;
    int tx = tid & 15, ty = tid >> 4;   // 1 row x 4 cols
    float acc[4] = {};
    for (int kc = 0; kc < 15; kc++) {
        int k0 = ks * 240 + kc * 16;
        __syncthreads();
        {
            int row = tid >> 4, kk = tid & 15;
            a_sh[row][kk] = cc[(size_t)(iq0 + row) * 2400 + k0 + kk];
        }
        #pragma unroll
        for (int t = 0; t < 4; t++) {
            int idx = tid + t * 256;
            int kk = idx >> 6, c2 = idx & 63;
            w_sh[kk][c2] = Wo[(size_t)(k0 + kk) * CS + cn0 + c2];
        }
        __syncthreads();
        #pragma unroll
        for (int kk = 0; kk < 16; kk++) {
            float a = a_sh[ty][kk];
            float4 b = *(const float4*)&w_sh[kk][tx * 4];
            acc[0] += a * b.x; acc[1] += a * b.y; acc[2] += a * b.z; acc[3] += a * b.w;
        }
    }
    int row = iq0 + ty;
    #pragma unroll
    for (int i = 0; i < 4; i++)
        atomicAdd(&out[(size_t)row * CS + cn0 + tx * 4 + i], acc[i]);
}

extern "C" void kernel_launch(void* const* d_in, const int* in_sizes, int n_in,
                              void* d_out, int out_size, void* d_ws, size_t ws_size,
                              hipStream_t stream)
{
    const float* s     = (const float*)d_in[0];
    const float* rot   = (const float*)d_in[1];
    const float* trans = (const float*)d_in[2];
    const float* z     = (const float*)d_in[3];
    const float* fm    = (const float*)d_in[4];
    const float* Wq    = (const float*)d_in[5];
    const float* bq    = (const float*)d_in[6];
    const float* Wkv   = (const float*)d_in[7];
    const float* bkv   = (const float*)d_in[8];
    const float* Wqp   = (const float*)d_in[9];
    const float* bqp   = (const float*)d_in[10];
    const float* Wkvp  = (const float*)d_in[11];
    const float* bkvp  = (const float*)d_in[12];
    const float* Wg    = (const float*)d_in[13];
    const float* bg    = (const float*)d_in[14];
    const float* gw    = (const float*)d_in[15];
    const float* dw    = (const float*)d_in[16];
    const float* hw    = (const float*)d_in[17];
    const float* Wo    = (const float*)d_in[18];
    const float* bo    = (const float*)d_in[19];

    float* ws   = (float*)d_ws;
    float* q    = ws;
    float* kv   = ws + 61440;
    float* qpt  = ws + 184320;
    float* kpt  = ws + 276480;
    float* vpt  = ws + 368640;
    float* att  = ws + 552960;
    float* qpr  = ws + 552960;   // overlays att (dead before k_att writes)
    float* kvpr = ws + 645120;
    float* gate = ws + 921600;
    float* og   = ws + 184320;   // overlays qpt/kpt (dead after k_att)
    float* cc   = ws + 1781760;
    float* out  = (float*)d_out;

    k_proj<<<dim3(37, 20), dim3(256), 0, stream>>>(s, Wq, bq, Wkv, bkv, Wqp, bqp,
                                                   Wkvp, bkvp, Wg, bg,
                                                   q, kv, qpr, kvpr, gate);
    k_points<<<dim3(LSEQ), dim3(192), 0, stream>>>(qpr, kvpr, gate, rot, trans, qpt, kpt, vpt);
    k_att<<<dim3(80, NH), dim3(256), 0, stream>>>(q, kv, qpt, kpt, fm, gw, dw, hw, att);
    k_initzero<<<dim3(4200), dim3(256), 0, stream>>>(bo, out, cc, og);
    k_sv<<<dim3(20, NH, 4), dim3(256), 0, stream>>>(att, kv, vpt, cc, og);
    k_pair<<<dim3(LSEQ, 5), dim3(256), 0, stream>>>(att, z, cc);
    k_finish<<<dim3(LSEQ), dim3(128), 0, stream>>>(og, rot, trans, cc);
    k_gemm<<<dim3(20, 6, 10), dim3(256), 0, stream>>>(cc, Wo, out);
}

// Round 6
// 223.876 us; speedup vs baseline: 1.6950x; 1.1732x over previous
//
#include <hip/hip_runtime.h>
#include <hip/hip_bf16.h>
#include <math.h>

#define LSEQ 320
#define CS 384
#define CZ 128
#define CH 16
#define NH 12
#define PQ 4
#define PV 8
#define EPSF 1e-8f

typedef short short8 __attribute__((ext_vector_type(8)));
typedef float f32x4 __attribute__((ext_vector_type(4)));

// float -> bf16 (RNE)
__device__ __forceinline__ unsigned short f2b(float x) {
    union { float f; unsigned u; } v; v.f = x;
    unsigned r = (v.u + 0x7FFF + ((v.u >> 16) & 1)) >> 16;
    return (unsigned short)r;
}
__device__ __forceinline__ float b2f(unsigned short h) {
    union { unsigned u; float f; } v; v.u = ((unsigned)h) << 16;
    return v.f;
}

// workspace float offsets (~21 MB total; ws is >=256MB per fillBuffer evidence)
#define OFF_Q      0         // fp32 [320][192]
#define OFF_KV     61440     // fp32 [320][384]
#define OFF_QPT    184320    // fp32 [320][48][6]
#define OFF_KPT    276480    // fp32 [320][48][6]
#define OFF_OG     368640    // fp32 [320][576]
#define OFF_ATTHI  552960    // bf16 [16][320][320] (planes 12-15 zeroed)
#define OFF_ATTLO  1372160   // bf16 [16][320][320]
#define OFF_CCHI   2191360   // bf16 [320][2400]
#define OFF_CCLO   2575360   // bf16 [320][2400]
#define OFF_SHI    2959360   // bf16 [320][384]
#define OFF_SLO    2990080
#define OFF_WCATHI 3020800   // bf16 [384][1776]
#define OFF_WCATLO 3361792
#define OFF_BCAT   3702784   // fp32 [1776]
#define OFF_WOHI   3704560   // bf16 [2400][384]
#define OFF_WOLO   4165360
#define OFF_VKVHI  4626160   // bf16 [12][64][320]
#define OFF_VKVLO  4749040
#define OFF_QPR    4871920   // fp32 [320][288]
#define OFF_KVPR   4964080   // fp32 [320][864]
#define OFF_GATE   5240560   // fp32 [320][48]

// ---------------- kernel 0: cast inputs to bf16 hi+lo ----------------
// items: s 122880 | wcat 681984 | bcat 1776 | wo 921600 -> 1728240
__global__ __launch_bounds__(256) void k_cast(
    const float* __restrict__ s,
    const float* __restrict__ Wq, const float* __restrict__ bq,
    const float* __restrict__ Wkv, const float* __restrict__ bkv,
    const float* __restrict__ Wqp, const float* __restrict__ bqp,
    const float* __restrict__ Wkvp, const float* __restrict__ bkvp,
    const float* __restrict__ Wg, const float* __restrict__ bg,
    const float* __restrict__ Wo,
    unsigned short* __restrict__ s_hi, unsigned short* __restrict__ s_lo,
    unsigned short* __restrict__ wcat_hi, unsigned short* __restrict__ wcat_lo,
    float* __restrict__ bcat,
    unsigned short* __restrict__ wo_hi, unsigned short* __restrict__ wo_lo)
{
    int i = blockIdx.x * 256 + threadIdx.x;
    if (i < 122880) {
        float x = s[i];
        unsigned short hi = f2b(x);
        s_hi[i] = hi; s_lo[i] = f2b(x - b2f(hi));
        return;
    }
    i -= 122880;
    if (i < 681984) {
        int k = i / 1776, c = i - k * 1776;
        float v;
        if (c < 192)       v = Wq[(size_t)k * 192 + c];
        else if (c < 576)  v = Wkv[(size_t)k * 384 + c - 192];
        else if (c < 864)  v = Wqp[(size_t)k * 288 + c - 576];
        else if (c < 1728) v = Wkvp[(size_t)k * 864 + c - 864];
        else               v = Wg[(size_t)k * 48 + c - 1728];
        unsigned short hi = f2b(v);
        wcat_hi[i] = hi; wcat_lo[i] = f2b(v - b2f(hi));
        return;
    }
    i -= 681984;
    if (i < 1776) {
        float v;
        if (i < 192)       v = bq[i];
        else if (i < 576)  v = bkv[i - 192];
        else if (i < 864)  v = bqp[i - 576];
        else if (i < 1728) v = bkvp[i - 864];
        else               v = bg[i - 1728];
        bcat[i] = v;
        return;
    }
    i -= 1776;
    if (i < 921600) {
        float v = Wo[i];
        unsigned short hi = f2b(v);
        wo_hi[i] = hi; wo_lo[i] = f2b(v - b2f(hi));
    }
}

// ---------------- kernel 1: projection GEMM, split-precision MFMA ----------------
// C[320 x 1776] = (s_hi+s_lo)@(w_hi+w_lo) + bcat (lo*lo dropped).
// grid (37 n-tiles of 48, 5 m-tiles of 64), 256 thr.
__global__ __launch_bounds__(256) void k_proj(
    const unsigned short* __restrict__ s_hi, const unsigned short* __restrict__ s_lo,
    const unsigned short* __restrict__ wcat_hi, const unsigned short* __restrict__ wcat_lo,
    const float* __restrict__ bcat,
    float* __restrict__ qo, float* __restrict__ kvo,
    float* __restrict__ qpr, float* __restrict__ kvpr, float* __restrict__ gate)
{
    __shared__ unsigned short a_hi[64][56];
    __shared__ unsigned short a_lo[64][56];
    __shared__ unsigned short w_hi[48][56];
    __shared__ unsigned short w_lo[48][56];
    int col0 = blockIdx.x * 48, l0 = blockIdx.y * 64;
    int tid = threadIdx.x;
    int lane = tid & 63, w = tid >> 6;
    int ncol = lane & 15, blk = lane >> 4, mrow = (lane >> 4) * 4;

    float* dst; int nc, cbase; bool sig = false;
    if (col0 < 192)       { nc = 192; cbase = col0;        dst = qo;   }
    else if (col0 < 576)  { nc = 384; cbase = col0 - 192;  dst = kvo;  }
    else if (col0 < 864)  { nc = 288; cbase = col0 - 576;  dst = qpr;  }
    else if (col0 < 1728) { nc = 864; cbase = col0 - 864;  dst = kvpr; }
    else                  { nc = 48;  cbase = 0;           dst = gate; sig = true; }

    f32x4 acc[3] = {};
    for (int k0 = 0; k0 < 384; k0 += 32) {
        __syncthreads();
        {
            int row = tid >> 2, seg = tid & 3;
            size_t off = (size_t)(l0 + row) * 384 + k0 + seg * 8;
            *(short8*)&a_hi[row][seg * 8] = *(const short8*)(s_hi + off);
            *(short8*)&a_lo[row][seg * 8] = *(const short8*)(s_lo + off);
        }
        if (tid < 96) {
            int kk = tid / 3, coff = (tid % 3) * 16;
            size_t off = (size_t)(k0 + kk) * 1776 + col0 + coff;
            short8 h0 = *(const short8*)(wcat_hi + off);
            short8 h1 = *(const short8*)(wcat_hi + off + 8);
            short8 l0v = *(const short8*)(wcat_lo + off);
            short8 l1v = *(const short8*)(wcat_lo + off + 8);
            #pragma unroll
            for (int i = 0; i < 8; i++) {
                w_hi[coff + i][kk]     = (unsigned short)h0[i];
                w_hi[coff + 8 + i][kk] = (unsigned short)h1[i];
                w_lo[coff + i][kk]     = (unsigned short)l0v[i];
                w_lo[coff + 8 + i][kk] = (unsigned short)l1v[i];
            }
        }
        __syncthreads();
        short8 afh = *(short8*)&a_hi[w * 16 + ncol][blk * 8];
        short8 afl = *(short8*)&a_lo[w * 16 + ncol][blk * 8];
        #pragma unroll
        for (int s3 = 0; s3 < 3; s3++) {
            short8 bfh = *(short8*)&w_hi[s3 * 16 + ncol][blk * 8];
            short8 bfl = *(short8*)&w_lo[s3 * 16 + ncol][blk * 8];
            acc[s3] = __builtin_amdgcn_mfma_f32_16x16x32_bf16(afh, bfh, acc[s3], 0, 0, 0);
            acc[s3] = __builtin_amdgcn_mfma_f32_16x16x32_bf16(afh, bfl, acc[s3], 0, 0, 0);
            acc[s3] = __builtin_amdgcn_mfma_f32_16x16x32_bf16(afl, bfh, acc[s3], 0, 0, 0);
        }
    }
    #pragma unroll
    for (int s3 = 0; s3 < 3; s3++) {
        float bv = bcat[col0 + s3 * 16 + ncol];
        int cloc = cbase + s3 * 16 + ncol;
        #pragma unroll
        for (int r = 0; r < 4; r++) {
            float v2 = acc[s3][r] + bv;
            if (sig) v2 = 1.0f / (1.0f + expf(-v2));
            dst[(size_t)(l0 + w * 16 + mrow + r) * nc + cloc] = v2;
        }
    }
}

// ---------------- kernel 2: frame transforms + build vkvT hi/lo ----------------
__global__ __launch_bounds__(256) void k_points(
    const float* __restrict__ qpr, const float* __restrict__ kvpr, const float* __restrict__ gate,
    const float* __restrict__ rot, const float* __restrict__ trans,
    const float* __restrict__ kv,
    float* __restrict__ qpt, float* __restrict__ kpt,
    unsigned short* __restrict__ vkv_hi, unsigned short* __restrict__ vkv_lo)
{
    __shared__ float vsh[96][6];
    int l = blockIdx.x, t = threadIdx.x;
    const float* R = rot + l * 9;
    float tx = trans[l * 3], ty = trans[l * 3 + 1], tz = trans[l * 3 + 2];
    if (t < 192) {
        const float* src; float g = 1.0f; float* dst = nullptr; int vj = -1;
        if (t < 48)      { src = qpr + (size_t)l * 288 + t * 6; g = gate[l * 48 + t]; dst = qpt + ((size_t)l * 48 + t) * 6; }
        else if (t < 96) { int j = t - 48; src = kvpr + (size_t)l * 864 + j * 6; dst = kpt + ((size_t)l * 48 + j) * 6; }
        else             { int j = t - 96; src = kvpr + (size_t)l * 864 + 288 + j * 6; vj = j; }
        float px = src[0], py = src[1], pz = src[2], ux = src[3], uy = src[4], uz = src[5];
        float c0 = R[0] * px + R[1] * py + R[2] * pz + tx;
        float c1 = R[3] * px + R[4] * py + R[5] * pz + ty;
        float c2 = R[6] * px + R[7] * py + R[8] * pz + tz;
        float d0 = R[0] * ux + R[1] * uy + R[2] * uz;
        float d1 = R[3] * ux + R[4] * uy + R[5] * uz;
        float d2 = R[6] * ux + R[7] * uy + R[8] * uz;
        if (vj >= 0) {
            vsh[vj][0] = c0; vsh[vj][1] = c1; vsh[vj][2] = c2;
            vsh[vj][3] = d0; vsh[vj][4] = d1; vsh[vj][5] = d2;
        } else {
            dst[0] = c0 * g; dst[1] = c1 * g; dst[2] = c2 * g;
            dst[3] = d0 * g; dst[4] = d1 * g; dst[5] = d2 * g;
        }
    }
    __syncthreads();
    #pragma unroll
    for (int e = 0; e < 3; e++) {
        int u = t * 3 + e;   // < 768
        int h = u >> 6, n = u & 63;
        float val;
        if (n < 16) val = kv[(size_t)l * 384 + 192 + h * 16 + n];
        else        val = vsh[h * 8 + (n - 16) / 6][(n - 16) % 6];
        unsigned short hi = f2b(val);
        size_t idx = ((size_t)h * 64 + n) * 320 + l;
        vkv_hi[idx] = hi;
        vkv_lo[idx] = f2b(val - b2f(hi));
    }
}

// ---------------- kernel 3: attention logits + softmax -> att hi/lo ----------------
// grid (80, 12), 256 thr = 4 waves (one iq per wave, all share h).
__global__ __launch_bounds__(256) void k_att(
    const float* __restrict__ qb, const float* __restrict__ kvb,
    const float* __restrict__ qpt, const float* __restrict__ kpt,
    const float* __restrict__ fm, const float* __restrict__ gw,
    const float* __restrict__ dwp, const float* __restrict__ hwp,
    unsigned short* __restrict__ att_hi, unsigned short* __restrict__ att_lo)
{
    __shared__ float kp_sh[320][25];
    int tid = threadIdx.x;
    int w = tid >> 6, lane = tid & 63;
    int iq = blockIdx.x * 4 + w;
    int h = blockIdx.y;

    for (int idx = tid; idx < 7680; idx += 256) {
        int kk = idx / 24, j = idx - kk * 24;
        kp_sh[kk][j] = kpt[(size_t)kk * 288 + h * 24 + j];
    }
    __syncthreads();

    float qv[CH];
    #pragma unroll
    for (int c = 0; c < CH; c++) qv[c] = qb[(size_t)iq * 192 + h * CH + c];
    float qp[24];
    #pragma unroll
    for (int j = 0; j < 24; j++) qp[j] = qpt[(size_t)iq * 288 + h * 24 + j];
    float nq[PQ];
    #pragma unroll
    for (int p = 0; p < PQ; p++) {
        float x = qp[p * 6 + 3], y = qp[p * 6 + 4], zz = qp[p * 6 + 5];
        nq[p] = sqrtf(x * x + y * y + zz * zz);
    }
    float dwv = dwp[0], g0 = gw[0], g1 = gw[1], hwv = hwp[h];
    float fmi = fm[iq];

    float lg[5];
    #pragma unroll
    for (int r = 0; r < 5; r++) {
        int kk = r * 64 + lane;
        const float* kp = &kp_sh[kk][0];

        float scalar = 0.f;
        #pragma unroll
        for (int c = 0; c < CH; c++) scalar += qv[c] * kvb[(size_t)kk * 384 + h * CH + c];
        scalar *= 0.25f;

        float pos = 0.f;
        #pragma unroll
        for (int p = 0; p < PQ; p++) {
            float dx = qp[p * 6] - kp[p * 6], dy = qp[p * 6 + 1] - kp[p * 6 + 1], dz = qp[p * 6 + 2] - kp[p * 6 + 2];
            float d = sqrtf(dx * dx + dy * dy + dz * dz);
            pos += d + logf(d + EPSF) + 1.0f / (d + EPSF);
        }
        pos *= 0.25f;

        float dir = 0.f;
        #pragma unroll
        for (int p = 0; p < PQ; p++) {
            float kx = kp[p * 6 + 3], ky = kp[p * 6 + 4], kz = kp[p * 6 + 5];
            float nk = sqrtf(kx * kx + ky * ky + kz * kz);
            float cm = 0.f;
            #pragma unroll
            for (int pq = 0; pq < PQ; pq++) {
                float qx = qp[pq * 6 + 3], qy = qp[pq * 6 + 4], qz = qp[pq * 6 + 5];
                float cx = qy * kz - qz * ky;
                float cy = qz * kx - qx * kz;
                float cz = qx * ky - qy * kx;
                cm += sqrtf(cx * cx + cy * cy + cz * cz);
            }
            cm *= 0.25f;
            float qx = qp[p * 6 + 3], qy = qp[p * 6 + 4], qz = qp[p * 6 + 5];
            float dotp = qx * kx + qy * ky + qz * kz;
            dir += dotp - cm / (nq[p] * nk + EPSF);
        }
        dir *= 0.25f;

        float logit = scalar + dwv * (g0 * pos + g1 * dir);
        logit *= hwv;
        logit += 100000.0f * (fmi * fm[kk] - 1.0f);
        lg[r] = logit;
    }

    float mx = lg[0];
    #pragma unroll
    for (int r = 1; r < 5; r++) mx = fmaxf(mx, lg[r]);
    for (int m = 32; m; m >>= 1) mx = fmaxf(mx, __shfl_xor(mx, m, 64));

    float e[5], sm = 0.f;
    #pragma unroll
    for (int r = 0; r < 5; r++) { e[r] = expf(lg[r] - mx); sm += e[r]; }
    for (int m = 32; m; m >>= 1) sm += __shfl_xor(sm, m, 64);
    float inv = 1.0f / sm;
    #pragma unroll
    for (int r = 0; r < 5; r++) {
        float p = e[r] * inv;
        unsigned short hi = f2b(p);
        size_t idx = ((size_t)h * 320 + iq) * 320 + r * 64 + lane;
        att_hi[idx] = hi;
        att_lo[idx] = f2b(p - b2f(hi));
    }
}

// ---------------- kernel 4: zero phantom att planes (hi+lo) + init out ----------
// items: 204800 + 204800 + 122880 = 532480 -> 2080 blocks
__global__ __launch_bounds__(256) void k_initzero(
    const float* __restrict__ bo, float* __restrict__ out,
    float* __restrict__ ph_hi, float* __restrict__ ph_lo)
{
    int i = blockIdx.x * 256 + threadIdx.x;
    if (i < 204800) ph_hi[i] = 0.0f;
    else if (i < 409600) ph_lo[i - 204800] = 0.0f;
    else { int j = i - 409600; out[j] = bo[j % CS]; }
}

// ---------------- kernel 5: o_scalar + o_geom via split MFMA ----------------
// per (iq-tile of 16, h): [16 x 320] @ [320 x 64]. grid (20,12), 64 thr.
__global__ __launch_bounds__(64) void k_sv(
    const unsigned short* __restrict__ att_hi, const unsigned short* __restrict__ att_lo,
    const unsigned short* __restrict__ vkv_hi, const unsigned short* __restrict__ vkv_lo,
    unsigned short* __restrict__ cc_hi, unsigned short* __restrict__ cc_lo,
    float* __restrict__ og)
{
    __shared__ unsigned short a_hi[16][56];
    __shared__ unsigned short a_lo[16][56];
    __shared__ unsigned short bt_hi[64][56];
    __shared__ unsigned short bt_lo[64][56];
    int iq0 = blockIdx.x * 16, h = blockIdx.y;
    int tid = threadIdx.x;
    int ncol = tid & 15, blk = tid >> 4, mrow = (tid >> 4) * 4;

    f32x4 acc[4] = {};
    for (int k0 = 0; k0 < 320; k0 += 32) {
        __syncthreads();
        {
            int row = tid >> 2, seg = tid & 3;
            size_t off = ((size_t)h * 320 + iq0 + row) * 320 + k0 + seg * 8;
            *(short8*)&a_hi[row][seg * 8] = *(const short8*)(att_hi + off);
            *(short8*)&a_lo[row][seg * 8] = *(const short8*)(att_lo + off);
        }
        {
            size_t off = ((size_t)h * 64 + tid) * 320 + k0;
            #pragma unroll
            for (int j2 = 0; j2 < 4; j2++) {
                *(short8*)&bt_hi[tid][j2 * 8] = *(const short8*)(vkv_hi + off + j2 * 8);
                *(short8*)&bt_lo[tid][j2 * 8] = *(const short8*)(vkv_lo + off + j2 * 8);
            }
        }
        __syncthreads();
        short8 afh = *(short8*)&a_hi[ncol][blk * 8];
        short8 afl = *(short8*)&a_lo[ncol][blk * 8];
        #pragma unroll
        for (int s4 = 0; s4 < 4; s4++) {
            short8 bfh = *(short8*)&bt_hi[s4 * 16 + ncol][blk * 8];
            short8 bfl = *(short8*)&bt_lo[s4 * 16 + ncol][blk * 8];
            acc[s4] = __builtin_amdgcn_mfma_f32_16x16x32_bf16(afh, bfh, acc[s4], 0, 0, 0);
            acc[s4] = __builtin_amdgcn_mfma_f32_16x16x32_bf16(afh, bfl, acc[s4], 0, 0, 0);
            acc[s4] = __builtin_amdgcn_mfma_f32_16x16x32_bf16(afl, bfh, acc[s4], 0, 0, 0);
        }
    }
    #pragma unroll
    for (int s4 = 0; s4 < 4; s4++) {
        int n = s4 * 16 + ncol;
        #pragma unroll
        for (int r = 0; r < 4; r++) {
            int iq = iq0 + mrow + r;
            float v = acc[s4][r];
            if (n < 16) {
                unsigned short hi = f2b(v);
                size_t idx = (size_t)iq * 2400 + h * 16 + n;
                cc_hi[idx] = hi;
                cc_lo[idx] = f2b(v - b2f(hi));
            } else {
                og[(size_t)iq * 576 + h * 48 + (n - 16)] = v;
            }
        }
    }
}

// ---------------- kernel 6: o_pair via MFMA (A=hi, z plain bf16) ----------------
// per iq: [16(h) x 320] @ [320 x 128]. grid (320), 256 thr.
__global__ __launch_bounds__(256) void k_pair(
    const unsigned short* __restrict__ att_hi, const float* __restrict__ z,
    unsigned short* __restrict__ cc_hi, unsigned short* __restrict__ cc_lo)
{
    __shared__ unsigned short a_sh[16][56];
    __shared__ unsigned short zt_sh[128][56];
    int iq = blockIdx.x;
    int tid = threadIdx.x;
    int lane = tid & 63, w = tid >> 6;
    int ncol = lane & 15, blk = lane >> 4, mrow = (lane >> 4) * 4;

    f32x4 acc[2] = {};
    for (int k0 = 0; k0 < 320; k0 += 32) {
        __syncthreads();
        if (tid < 64) {
            int row = tid >> 2, seg = tid & 3;
            *(short8*)&a_sh[row][seg * 8] =
                *(const short8*)(att_hi + (size_t)row * 102400 + (size_t)iq * 320 + k0 + seg * 8);
        }
        {
            int kk = tid >> 3, cb = (tid & 7) * 16;
            const float* src = z + ((size_t)iq * 320 + k0 + kk) * 128 + cb;
            #pragma unroll
            for (int g4 = 0; g4 < 4; g4++) {
                float4 f = *(const float4*)(src + g4 * 4);
                zt_sh[cb + g4 * 4 + 0][kk] = f2b(f.x);
                zt_sh[cb + g4 * 4 + 1][kk] = f2b(f.y);
                zt_sh[cb + g4 * 4 + 2][kk] = f2b(f.z);
                zt_sh[cb + g4 * 4 + 3][kk] = f2b(f.w);
            }
        }
        __syncthreads();
        short8 af = *(short8*)&a_sh[ncol][blk * 8];
        #pragma unroll
        for (int s2 = 0; s2 < 2; s2++) {
            short8 bf = *(short8*)&zt_sh[w * 32 + s2 * 16 + ncol][blk * 8];
            acc[s2] = __builtin_amdgcn_mfma_f32_16x16x32_bf16(af, bf, acc[s2], 0, 0, 0);
        }
    }
    #pragma unroll
    for (int s2 = 0; s2 < 2; s2++) {
        int n = w * 32 + s2 * 16 + ncol;
        #pragma unroll
        for (int r = 0; r < 4; r++) {
            int h = mrow + r;
            if (h < 12) {
                float v = acc[s2][r];
                unsigned short hi = f2b(v);
                size_t idx = (size_t)iq * 2400 + 864 + h * 128 + n;
                cc_hi[idx] = hi;
                cc_lo[idx] = f2b(v - b2f(hi));
            }
        }
    }
}

// ---------------- kernel 7: inverse-frame transform -> cc geom7 hi/lo ----------------
__global__ __launch_bounds__(96) void k_finish(
    const float* __restrict__ og, const float* __restrict__ rot, const float* __restrict__ trans,
    unsigned short* __restrict__ cc_hi, unsigned short* __restrict__ cc_lo)
{
    int iq = blockIdx.x, tid = threadIdx.x;
    int h = tid / PV, p = tid % PV;
    const float* R = rot + iq * 9;
    float tx = trans[iq * 3], ty = trans[iq * 3 + 1], tz = trans[iq * 3 + 2];
    const float* o = og + (size_t)iq * 576 + h * 48 + p * 6;
    float gx = o[0] - tx, gy = o[1] - ty, gz = o[2] - tz;
    float l0 = R[0] * gx + R[3] * gy + R[6] * gz;
    float l1 = R[1] * gx + R[4] * gy + R[7] * gz;
    float l2 = R[2] * gx + R[5] * gy + R[8] * gz;
    float dx = o[3], dy = o[4], dz = o[5];
    float e0 = R[0] * dx + R[3] * dy + R[6] * dz;
    float e1 = R[1] * dx + R[4] * dy + R[7] * dz;
    float e2 = R[2] * dx + R[5] * dy + R[8] * dz;
    float n = sqrtf(e0 * e0 + e1 * e1 + e2 * e2);
    float inv = 1.0f / fmaxf(n, 1e-12f);
    float ln = sqrtf(l0 * l0 + l1 * l1 + l2 * l2);
    float vals[7] = { l0, l1, l2, e0 * inv, e1 * inv, e2 * inv, ln };
    size_t base = (size_t)iq * 2400 + 192 + (h * PV + p) * 7;
    #pragma unroll
    for (int j = 0; j < 7; j++) {
        unsigned short hi = f2b(vals[j]);
        cc_hi[base + j] = hi;
        cc_lo[base + j] = f2b(vals[j] - b2f(hi));
    }
}

// ---------------- kernel 8: out += cc @ Wo via split MFMA, split-K ----------------
// grid (5 m-tiles of 64, 8 n-tiles of 48, 5 k-splits of 480), 256 thr.
__global__ __launch_bounds__(256) void k_gemm(
    const unsigned short* __restrict__ cc_hi, const unsigned short* __restrict__ cc_lo,
    const unsigned short* __restrict__ wo_hi, const unsigned short* __restrict__ wo_lo,
    float* __restrict__ out)
{
    __shared__ unsigned short a_hi[64][56];
    __shared__ unsigned short a_lo[64][56];
    __shared__ unsigned short w_hi[48][56];
    __shared__ unsigned short w_lo[48][56];
    int iq0 = blockIdx.x * 64, col0 = blockIdx.y * 48, ks = blockIdx.z;
    int tid = threadIdx.x;
    int lane = tid & 63, w = tid >> 6;
    int ncol = lane & 15, blk = lane >> 4, mrow = (lane >> 4) * 4;

    f32x4 acc[3] = {};
    for (int kc = 0; kc < 15; kc++) {
        int k0 = ks * 480 + kc * 32;
        __syncthreads();
        {
            int row = tid >> 2, seg = tid & 3;
            size_t off = (size_t)(iq0 + row) * 2400 + k0 + seg * 8;
            *(short8*)&a_hi[row][seg * 8] = *(const short8*)(cc_hi + off);
            *(short8*)&a_lo[row][seg * 8] = *(const short8*)(cc_lo + off);
        }
        if (tid < 96) {
            int kk = tid / 3, coff = (tid % 3) * 16;
            size_t off = (size_t)(k0 + kk) * 384 + col0 + coff;
            short8 h0 = *(const short8*)(wo_hi + off);
            short8 h1 = *(const short8*)(wo_hi + off + 8);
            short8 l0v = *(const short8*)(wo_lo + off);
            short8 l1v = *(const short8*)(wo_lo + off + 8);
            #pragma unroll
            for (int i = 0; i < 8; i++) {
                w_hi[coff + i][kk]     = (unsigned short)h0[i];
                w_hi[coff + 8 + i][kk] = (unsigned short)h1[i];
                w_lo[coff + i][kk]     = (unsigned short)l0v[i];
                w_lo[coff + 8 + i][kk] = (unsigned short)l1v[i];
            }
        }
        __syncthreads();
        short8 afh = *(short8*)&a_hi[w * 16 + ncol][blk * 8];
        short8 afl = *(short8*)&a_lo[w * 16 + ncol][blk * 8];
        #pragma unroll
        for (int s3 = 0; s3 < 3; s3++) {
            short8 bfh = *(short8*)&w_hi[s3 * 16 + ncol][blk * 8];
            short8 bfl = *(short8*)&w_lo[s3 * 16 + ncol][blk * 8];
            acc[s3] = __builtin_amdgcn_mfma_f32_16x16x32_bf16(afh, bfh, acc[s3], 0, 0, 0);
            acc[s3] = __builtin_amdgcn_mfma_f32_16x16x32_bf16(afh, bfl, acc[s3], 0, 0, 0);
            acc[s3] = __builtin_amdgcn_mfma_f32_16x16x32_bf16(afl, bfh, acc[s3], 0, 0, 0);
        }
    }
    #pragma unroll
    for (int s3 = 0; s3 < 3; s3++) {
        int cn = col0 + s3 * 16 + ncol;
        #pragma unroll
        for (int r = 0; r < 4; r++)
            atomicAdd(&out[(size_t)(iq0 + w * 16 + mrow + r) * CS + cn], acc[s3][r]);
    }
}

extern "C" void kernel_launch(void* const* d_in, const int* in_sizes, int n_in,
                              void* d_out, int out_size, void* d_ws, size_t ws_size,
                              hipStream_t stream)
{
    const float* s     = (const float*)d_in[0];
    const float* rot   = (const float*)d_in[1];
    const float* trans = (const float*)d_in[2];
    const float* z     = (const float*)d_in[3];
    const float* fm    = (const float*)d_in[4];
    const float* Wq    = (const float*)d_in[5];
    const float* bq    = (const float*)d_in[6];
    const float* Wkv   = (const float*)d_in[7];
    const float* bkv   = (const float*)d_in[8];
    const float* Wqp   = (const float*)d_in[9];
    const float* bqp   = (const float*)d_in[10];
    const float* Wkvp  = (const float*)d_in[11];
    const float* bkvp  = (const float*)d_in[12];
    const float* Wg    = (const float*)d_in[13];
    const float* bg    = (const float*)d_in[14];
    const float* gw    = (const float*)d_in[15];
    const float* dw    = (const float*)d_in[16];
    const float* hw    = (const float*)d_in[17];
    const float* Wo    = (const float*)d_in[18];
    const float* bo    = (const float*)d_in[19];

    float* ws = (float*)d_ws;
    float*          q       = ws + OFF_Q;
    float*          kv      = ws + OFF_KV;
    float*          qpt     = ws + OFF_QPT;
    float*          kpt     = ws + OFF_KPT;
    float*          og      = ws + OFF_OG;
    unsigned short* att_hi  = (unsigned short*)(ws + OFF_ATTHI);
    unsigned short* att_lo  = (unsigned short*)(ws + OFF_ATTLO);
    float*          ph_hi   = ws + OFF_ATTHI + 12 * 51200;
    float*          ph_lo   = ws + OFF_ATTLO + 12 * 51200;
    unsigned short* cc_hi   = (unsigned short*)(ws + OFF_CCHI);
    unsigned short* cc_lo   = (unsigned short*)(ws + OFF_CCLO);
    unsigned short* s_hi    = (unsigned short*)(ws + OFF_SHI);
    unsigned short* s_lo    = (unsigned short*)(ws + OFF_SLO);
    unsigned short* wcat_hi = (unsigned short*)(ws + OFF_WCATHI);
    unsigned short* wcat_lo = (unsigned short*)(ws + OFF_WCATLO);
    float*          bcat    = ws + OFF_BCAT;
    unsigned short* wo_hi   = (unsigned short*)(ws + OFF_WOHI);
    unsigned short* wo_lo   = (unsigned short*)(ws + OFF_WOLO);
    unsigned short* vkv_hi  = (unsigned short*)(ws + OFF_VKVHI);
    unsigned short* vkv_lo  = (unsigned short*)(ws + OFF_VKVLO);
    float*          qpr     = ws + OFF_QPR;
    float*          kvpr    = ws + OFF_KVPR;
    float*          gate    = ws + OFF_GATE;
    float* out = (float*)d_out;

    k_cast<<<dim3(6752), dim3(256), 0, stream>>>(s, Wq, bq, Wkv, bkv, Wqp, bqp,
                                                 Wkvp, bkvp, Wg, bg, Wo,
                                                 s_hi, s_lo, wcat_hi, wcat_lo, bcat,
                                                 wo_hi, wo_lo);
    k_proj<<<dim3(37, 5), dim3(256), 0, stream>>>(s_hi, s_lo, wcat_hi, wcat_lo, bcat,
                                                  q, kv, qpr, kvpr, gate);
    k_points<<<dim3(LSEQ), dim3(256), 0, stream>>>(qpr, kvpr, gate, rot, trans, kv,
                                                   qpt, kpt, vkv_hi, vkv_lo);
    k_att<<<dim3(80, NH), dim3(256), 0, stream>>>(q, kv, qpt, kpt, fm, gw, dw, hw,
                                                  att_hi, att_lo);
    k_initzero<<<dim3(2080), dim3(256), 0, stream>>>(bo, out, ph_hi, ph_lo);
    k_sv<<<dim3(20, NH), dim3(64), 0, stream>>>(att_hi, att_lo, vkv_hi, vkv_lo,
                                                cc_hi, cc_lo, og);
    k_pair<<<dim3(LSEQ), dim3(256), 0, stream>>>(att_hi, z, cc_hi, cc_lo);
    k_finish<<<dim3(LSEQ), dim3(96), 0, stream>>>(og, rot, trans, cc_hi, cc_lo);
    k_gemm<<<dim3(5, 8, 5), dim3(256), 0, stream>>>(cc_hi, cc_lo, wo_hi, wo_lo, out);
}